// Round 4
// baseline (13539.204 us; speedup 1.0000x reference)
//
#include <hip/hip_runtime.h>

// LSTM: T=1024, B=64, IN=H=512.
// 64 persistent WGs x 512 threads (2 batch groups x 32 WGs). Each WG owns 16
// hidden units (64 gate rows) for 32 batches. Waves (k2 = wave>>2, n4 = wave&3):
//   k2=0: x-projection GEMM for gate n4, K=512, A direct from global (cached),
//   k2=1: h-projection GEMM for gate n4, K=512, A staged once into LDS (f16)
//         via cache-bypassing (sc0 sc1) loads -- 4 MB/step total LLC traffic
//         (4x less than round 2's per-wave broadcast).
// Weights live in registers as f16 B-fragments (loaded once). h exchange via
// d_out h_seq with write-through stores; per-step flags in d_ws. No L2-wide
// cache maintenance anywhere. All asm outputs are EARLY-CLOBBER ("=&v") --
// round 3's crash was the allocator overlapping async-load outputs with the
// dead address operand. Static LDS kept at 57 KB (< 64 KB).

#define TT 1024
#define BB 64
#define DD 512
#define WPG 32
#define UPW 16
#define HSEQ ((size_t)TT * BB * DD)

// LDS h-tile: 32 rows x 512 f16 as 8 segs of 64 f16; seg stride 72, row
// stride 584 (both ≡ 4 banks mod 32 -> staging writes and frag reads ≤2-way).
#define SEGS 72
#define ROWSTRIDE 584

typedef _Float16 half8 __attribute__((ext_vector_type(8)));
typedef float f32x4 __attribute__((ext_vector_type(4)));

__device__ __forceinline__ float sigm(float v) { return 1.0f / (1.0f + __expf(-v)); }
__device__ __forceinline__ float tanh_fast(float v) { return 2.0f / (1.0f + __expf(-2.0f * v)) - 1.0f; }

#define CVT8(DST, LO, HI) do { \
    DST[0] = (_Float16)LO[0]; DST[1] = (_Float16)LO[1]; \
    DST[2] = (_Float16)LO[2]; DST[3] = (_Float16)LO[3]; \
    DST[4] = (_Float16)HI[0]; DST[5] = (_Float16)HI[1]; \
    DST[6] = (_Float16)HI[2]; DST[7] = (_Float16)HI[3]; } while (0)

// 64 consecutive f32 via 16 bypassing dwordx4 loads, ONE vmcnt, cvt->LDS f16.
// All outputs early-clobber: async data returns must not alias the address.
__device__ __forceinline__ void stage_coh(const float* p, _Float16* dst) {
    f32x4 r0, r1, r2, r3, r4, r5, r6, r7, r8, r9, r10, r11, r12, r13, r14, r15;
    asm volatile(
        "global_load_dwordx4 %0, %16, off sc0 sc1\n\t"
        "global_load_dwordx4 %1, %16, off offset:16 sc0 sc1\n\t"
        "global_load_dwordx4 %2, %16, off offset:32 sc0 sc1\n\t"
        "global_load_dwordx4 %3, %16, off offset:48 sc0 sc1\n\t"
        "global_load_dwordx4 %4, %16, off offset:64 sc0 sc1\n\t"
        "global_load_dwordx4 %5, %16, off offset:80 sc0 sc1\n\t"
        "global_load_dwordx4 %6, %16, off offset:96 sc0 sc1\n\t"
        "global_load_dwordx4 %7, %16, off offset:112 sc0 sc1\n\t"
        "global_load_dwordx4 %8, %16, off offset:128 sc0 sc1\n\t"
        "global_load_dwordx4 %9, %16, off offset:144 sc0 sc1\n\t"
        "global_load_dwordx4 %10, %16, off offset:160 sc0 sc1\n\t"
        "global_load_dwordx4 %11, %16, off offset:176 sc0 sc1\n\t"
        "global_load_dwordx4 %12, %16, off offset:192 sc0 sc1\n\t"
        "global_load_dwordx4 %13, %16, off offset:208 sc0 sc1\n\t"
        "global_load_dwordx4 %14, %16, off offset:224 sc0 sc1\n\t"
        "global_load_dwordx4 %15, %16, off offset:240 sc0 sc1\n\t"
        "s_waitcnt vmcnt(0)"
        : "=&v"(r0), "=&v"(r1), "=&v"(r2), "=&v"(r3),
          "=&v"(r4), "=&v"(r5), "=&v"(r6), "=&v"(r7),
          "=&v"(r8), "=&v"(r9), "=&v"(r10), "=&v"(r11),
          "=&v"(r12), "=&v"(r13), "=&v"(r14), "=&v"(r15)
        : "v"(p)
        : "memory");
    half8 h;
    CVT8(h, r0, r1);   *(half8*)(dst + 0)  = h;
    CVT8(h, r2, r3);   *(half8*)(dst + 8)  = h;
    CVT8(h, r4, r5);   *(half8*)(dst + 16) = h;
    CVT8(h, r6, r7);   *(half8*)(dst + 24) = h;
    CVT8(h, r8, r9);   *(half8*)(dst + 32) = h;
    CVT8(h, r10, r11); *(half8*)(dst + 40) = h;
    CVT8(h, r12, r13); *(half8*)(dst + 48) = h;
    CVT8(h, r14, r15); *(half8*)(dst + 56) = h;
}

__global__ __launch_bounds__(512) void lstm_persist(
    const float* __restrict__ x,
    const float* __restrict__ Wxf, const float* __restrict__ Whf,
    const float* __restrict__ Wxi, const float* __restrict__ Whi,
    const float* __restrict__ Wxo, const float* __restrict__ Who,
    const float* __restrict__ Wxg, const float* __restrict__ Whg,
    const float* __restrict__ bxf, const float* __restrict__ bhf,
    const float* __restrict__ bxi, const float* __restrict__ bhi,
    const float* __restrict__ bxo, const float* __restrict__ bho,
    const float* __restrict__ bxg, const float* __restrict__ bhg,
    float* out, int* flags)
{
    const int wg   = blockIdx.x;
    const int grp  = wg >> 5;        // batch group 0..1
    const int w    = wg & 31;        // unit-owner 0..31 (units w*16..w*16+15)
    const int tid  = threadIdx.x;
    const int wave = tid >> 6;
    const int k2   = wave >> 2;      // 0: x-GEMM, 1: h-GEMM
    const int n4   = wave & 3;       // gate index f,i,o,g
    const int lane = tid & 63;
    const int quad = lane >> 4;
    const int l16  = lane & 15;
    // h-staging role (k2=1 waves): 4 waves cover 32 rows x 8 segs
    const int srow = (n4 << 3) + (lane & 7);
    const int sseg = lane >> 3;

    __shared__ _Float16 h16[32 * ROWSTRIDE];   // 37376 B
    __shared__ float zbuf[2][32][68];          // 17408 B (pad 68: ≤2-way)
    __shared__ float c_lds[32][UPW];           // 2048 B
    __shared__ float bias_lds[64];             // 256 B   -> total ~57 KB

    c_lds[tid >> 4][tid & 15] = 0.0f;
    if (tid < 64) {
        const int g = tid >> 4, u = tid & 15;
        const float* bx = (g == 0) ? bxf : (g == 1) ? bxi : (g == 2) ? bxo : bxg;
        const float* bh = (g == 0) ? bhf : (g == 1) ? bhi : (g == 2) ? bho : bhg;
        bias_lds[tid] = bx[w * UPW + u] + bh[w * UPW + u];
    }

    // ---- weight B-fragments (once): wave (k2,n4) holds gate n4's rows
    // w*16..w*16+15, full K=512 of Wx (k2=0) or Wh (k2=1) ----
    const float* Wg_x = (n4 == 0) ? Wxf : (n4 == 1) ? Wxi : (n4 == 2) ? Wxo : Wxg;
    const float* Wg_h = (n4 == 0) ? Whf : (n4 == 1) ? Whi : (n4 == 2) ? Who : Whg;
    const float* Wsel = k2 ? Wg_h : Wg_x;
    const int wrow = w * UPW + l16;
    half8 wfrag[16];
#pragma unroll
    for (int kc = 0; kc < 16; ++kc) {
        const float* p = Wsel + (size_t)wrow * DD + kc * 32 + quad * 8;
        f32x4 lo = *(const f32x4*)p;
        f32x4 hi = *(const f32x4*)(p + 4);
        half8 f;
        CVT8(f, lo, hi);
        wfrag[kc] = f;
    }
    __syncthreads();

    for (int t = 0; t < TT; ++t) {
        if (k2 == 0) {
            // ---- x-GEMM: A direct from global (cached), 16 K-chunks ----
            f32x4 acc0 = {0.f, 0.f, 0.f, 0.f};
            f32x4 acc1 = {0.f, 0.f, 0.f, 0.f};
            const float* pa0 = x + ((size_t)t * BB + grp * 32 + l16) * DD + quad * 8;
            const float* pa1 = pa0 + 16 * DD;
#pragma unroll
            for (int kc = 0; kc < 16; ++kc) {
                f32x4 a0lo = *(const f32x4*)(pa0 + kc * 32);
                f32x4 a0hi = *(const f32x4*)(pa0 + kc * 32 + 4);
                f32x4 a1lo = *(const f32x4*)(pa1 + kc * 32);
                f32x4 a1hi = *(const f32x4*)(pa1 + kc * 32 + 4);
                half8 a0, a1;
                CVT8(a0, a0lo, a0hi);
                CVT8(a1, a1lo, a1hi);
                acc0 = __builtin_amdgcn_mfma_f32_16x16x32_f16(a0, wfrag[kc], acc0, 0, 0, 0);
                acc1 = __builtin_amdgcn_mfma_f32_16x16x32_f16(a1, wfrag[kc], acc1, 0, 0, 0);
            }
#pragma unroll
            for (int i = 0; i < 4; ++i) {
                zbuf[0][quad * 4 + i][n4 * 16 + l16]      = acc0[i];
                zbuf[0][16 + quad * 4 + i][n4 * 16 + l16] = acc1[i];
            }
        } else if (t > 0) {
            // ---- wait for all 32 producers of this group at step t-1 ----
            const int* fl = flags + ((grp * TT + (t - 1)) << 5) + (lane & 31);
            int f;
            asm volatile("global_load_dword %0, %1, off sc0 sc1\n\ts_waitcnt vmcnt(0)"
                         : "=&v"(f) : "v"(fl) : "memory");
            while (__ballot(f == 0) != 0ull) {
                __builtin_amdgcn_s_sleep(1);
                asm volatile("global_load_dword %0, %1, off sc0 sc1\n\ts_waitcnt vmcnt(0)"
                             : "=&v"(f) : "v"(fl) : "memory");
            }
            // ---- stage h-tile into LDS (once per WG) ----
            const float* src = out + ((size_t)(t - 1) * BB + grp * 32 + srow) * DD + sseg * 64;
            stage_coh(src, h16 + srow * ROWSTRIDE + sseg * SEGS);
        }
        __syncthreads();   // B1: h16 + zbuf[0] ready

        if (k2 == 1) {
            // ---- h-GEMM from LDS, 16 K-chunks ----
            f32x4 acc0 = {0.f, 0.f, 0.f, 0.f};
            f32x4 acc1 = {0.f, 0.f, 0.f, 0.f};
            if (t > 0) {
                const _Float16* base0 = h16 + l16 * ROWSTRIDE;
                const _Float16* base1 = h16 + (l16 + 16) * ROWSTRIDE;
#pragma unroll
                for (int kc = 0; kc < 16; ++kc) {
                    const int off = (kc >> 1) * SEGS + (kc & 1) * 32 + quad * 8;
                    half8 a0 = *(const half8*)(base0 + off);
                    half8 a1 = *(const half8*)(base1 + off);
                    acc0 = __builtin_amdgcn_mfma_f32_16x16x32_f16(a0, wfrag[kc], acc0, 0, 0, 0);
                    acc1 = __builtin_amdgcn_mfma_f32_16x16x32_f16(a1, wfrag[kc], acc1, 0, 0, 0);
                }
            }
#pragma unroll
            for (int i = 0; i < 4; ++i) {
                zbuf[1][quad * 4 + i][n4 * 16 + l16]      = acc0[i];
                zbuf[1][16 + quad * 4 + i][n4 * 16 + l16] = acc1[i];
            }
        }
        __syncthreads();   // B2: all z partials ready

        // ---- elementwise: 512 threads = 32 batches x 16 units ----
        {
            const int b = tid >> 4, u = tid & 15;
            float zf = bias_lds[u]      + zbuf[0][b][u]      + zbuf[1][b][u];
            float zi = bias_lds[16 + u] + zbuf[0][b][16 + u] + zbuf[1][b][16 + u];
            float zo = bias_lds[32 + u] + zbuf[0][b][32 + u] + zbuf[1][b][32 + u];
            float zg = bias_lds[48 + u] + zbuf[0][b][48 + u] + zbuf[1][b][48 + u];
            float ff = sigm(zf), ig = sigm(zi), og = sigm(zo), gg = tanh_fast(zg);
            float c  = ff * c_lds[b][u] + ig * gg;
            c_lds[b][u] = c;
            float h  = og * tanh_fast(c);
            const size_t col = (size_t)(grp * 32 + b) * DD + w * UPW + u;
            float* hp = out + (size_t)t * BB * DD + col;
            // write-through: h_seq output doubles as the exchange buffer
            asm volatile("global_store_dword %0, %1, off sc0 sc1"
                         :: "v"(hp), "v"(h) : "memory");
            if (t == TT - 1) out[HSEQ + col] = h;   // final h output
        }
        asm volatile("s_waitcnt vmcnt(0)" ::: "memory");   // drain own h stores
        __syncthreads();   // B3: whole WG's h stores drained
        if (tid == 0) {
            int one = 1;
            int* fp = flags + ((grp * TT + t) << 5) + w;
            asm volatile("global_store_dword %0, %1, off sc0 sc1"
                         :: "v"(fp), "v"(one) : "memory");
        }
    }

    // ---- final c output ----
    {
        const int b = tid >> 4, u = tid & 15;
        out[HSEQ + (size_t)BB * DD + (size_t)(grp * 32 + b) * DD + w * UPW + u] = c_lds[b][u];
    }
}

extern "C" void kernel_launch(void* const* d_in, const int* in_sizes, int n_in,
                              void* d_out, int out_size, void* d_ws, size_t ws_size,
                              hipStream_t stream) {
    const float* x   = (const float*)d_in[0];
    const float* Wxf = (const float*)d_in[1];  const float* bxf = (const float*)d_in[2];
    const float* Whf = (const float*)d_in[3];  const float* bhf = (const float*)d_in[4];
    const float* Wxi = (const float*)d_in[5];  const float* bxi = (const float*)d_in[6];
    const float* Whi = (const float*)d_in[7];  const float* bhi = (const float*)d_in[8];
    const float* Wxo = (const float*)d_in[9];  const float* bxo = (const float*)d_in[10];
    const float* Who = (const float*)d_in[11]; const float* bho = (const float*)d_in[12];
    const float* Wxg = (const float*)d_in[13]; const float* bxg = (const float*)d_in[14];
    const float* Whg = (const float*)d_in[15]; const float* bhg = (const float*)d_in[16];
    float* out = (float*)d_out;
    int* flags = (int*)d_ws;

    // flags are poisoned 0xAA before every timed launch -> zero them
    hipMemsetAsync(d_ws, 0, (size_t)2 * TT * WPG * sizeof(int), stream);

    void* args[] = { &x,
                     &Wxf, &Whf, &Wxi, &Whi, &Wxo, &Who, &Wxg, &Whg,
                     &bxf, &bhf, &bxi, &bhi, &bxo, &bho, &bxg, &bhg,
                     &out, &flags };
    hipLaunchCooperativeKernel((const void*)lstm_persist,
                               dim3(2 * WPG), dim3(512), args, 0, stream);
}